// Round 4
// baseline (298.656 us; speedup 1.0000x reference)
//
#include <hip/hip_runtime.h>
#include <math.h>

// SpectralConv3d via DHT identities — R4: 3-dispatch pipeline (gap-reduction theory).
//   r = Re(F) - Im(G);  ||r||^2 = (N^3/2)(2*sum x^2 + c1 - c2)
//   corner: n3->k3 + n2->k2 fused (k_fwd1), n1->k1 (k_fwd2s)
//   mix: conv = 0.5*sum_i[(x+xn)w + (x-xn)wn]; ||Y||^2 = (N^3/2)(2*sum conv^2 + conv000^2)
//   expand: n1->k1 + n2->k2 + n3->k3 all inside k_mixexp (wave-owned k1 sets, no barriers).
//
// R4 changes vs 276us R3 (theory: ~75us of the ~135us kernel window is dispatch gaps):
//   - 5 -> 3 dispatches: k_init dropped (fwd1 uses in-block LDS twiddles, R1-proven);
//     k_mixA + k_expBC fused into k_mixexp.
//   - k_mixexp grid (2,128): each block does full conv + full norm (duplicated, cheap),
//     then expansion for its 32-k1 half; waves own disjoint k1 sets and private LDS
//     (A1L rows / B2 buffers) -> zero __syncthreads after the conv barrier; within-wave
//     LDS ordering via inline s_waitcnt lgkmcnt(0).

constexpr int NT = 262144;  // 64^3
constexpr float TWOPI_64 = 0.09817477042468103f;  // 2*pi/64

// ws float offsets:
//   S     [128][64][2][64][2] : 2097152 at 0
//   red1p [128][33][3]        : 12672   at 2097152
//   xh    [128][512]          : 65536   at 2109824

// ---------------- K1: stage1 (n3->k3) + stage2 (n2->k2) + norm partials ----------------
__global__ __launch_bounds__(256) void k_fwd1(const float* __restrict__ x,
                                              float* __restrict__ S,
                                              float* __restrict__ red1p) {
  __shared__ float As[64 * 68];   // pad 68: 16B-aligned rows, banks spread
  __shared__ float Bs[64 * 68];
  __shared__ float PL[32 * 68];   // stage1 output: rr = row*16 + f*8 + k3; b128 rows
  __shared__ float tw1[1024];     // [n3 64][k3q 4][c(k3q),s(k3q),c(k3q+4),s(k3q+4)]
  __shared__ float rsm[12];
  const int t = threadIdx.x;
  const int j = blockIdx.x;       // 0..32
  const int bc = blockIdx.y;      // 0..127
  const int n1a = j, n1b = (64 - j) & 63;
  const bool paired = (n1a != n1b);
  for (int u = t; u < 1024; u += 256) {
    int n3 = u >> 4, k3q = (u >> 2) & 3, jj = u & 3;
    int k3 = k3q + ((jj >> 1) << 2);
    float ang = TWOPI_64 * (float)((k3 * n3) & 63);
    tw1[u] = (jj & 1) ? sinf(ang) : cosf(ang);
  }
  // stage-2 rotation seed (loop-invariant per thread)
  const int k2s = t & 7;
  const float angs = TWOPI_64 * (float)k2s;
  const float dc2 = cosf(angs), ds2 = sinf(angs);
  const float4* xa4 = (const float4*)(x + ((size_t)bc << 18) + (n1a << 12));
  const float4* xb4 = (const float4*)(x + ((size_t)bc << 18) + (n1b << 12));
  float ssp = 0.f;
  for (int q = 0; q < 4; ++q) {
    int l4 = t + (q << 8);
    int fl = l4 << 2;
    int r = fl >> 6, c = fl & 63;
    float4 va = xa4[l4], vb = xb4[l4];
    *(float4*)&As[r * 68 + c] = va;
    *(float4*)&Bs[r * 68 + c] = vb;
    ssp += va.x * va.x + va.y * va.y + va.z * va.z + va.w * va.w;
    if (paired) ssp += vb.x * vb.x + vb.y * vb.y + vb.z * vb.z + vb.w * vb.w;
  }
  __syncthreads();
  const int n2 = t & 63;
  const int k3q = t >> 6;
  {  // stage 1: contract n3 for k3q,k3q+4 over rows A,B; tw1 b128 wave-uniform broadcast
    float reA0 = 0, imA0 = 0, reA1 = 0, imA1 = 0;
    float reB0 = 0, imB0 = 0, reB1 = 0, imB1 = 0;
    const float4* Ar = (const float4*)&As[n2 * 68];
    const float4* Br = (const float4*)&Bs[n2 * 68];
    const float4* T4 = (const float4*)tw1;
    for (int m = 0; m < 16; ++m) {
      float4 va = Ar[m], vb = Br[m];
      float av[4] = {va.x, va.y, va.z, va.w};
      float bv[4] = {vb.x, vb.y, vb.z, vb.w};
#pragma unroll
      for (int e = 0; e < 4; ++e) {
        float4 tw = T4[(m << 4) + (e << 2) + k3q];
        float a = av[e], b = bv[e];
        reA0 += a * tw.x; imA0 -= a * tw.y;
        reB0 += b * tw.x; imB0 -= b * tw.y;
        reA1 += a * tw.z; imA1 -= a * tw.w;
        reB1 += b * tw.z; imB1 -= b * tw.w;
      }
    }
    PL[(k3q) * 68 + n2] = reA0;       PL[(8 + k3q) * 68 + n2] = imA0;
    PL[(16 + k3q) * 68 + n2] = reB0;  PL[(24 + k3q) * 68 + n2] = imB0;
    PL[(4 + k3q) * 68 + n2] = reA1;   PL[(12 + k3q) * 68 + n2] = imA1;
    PL[(20 + k3q) * 68 + n2] = reB1;  PL[(28 + k3q) * 68 + n2] = imB1;
  }
  // norm partials c1,c2 (ss done at load)
  float c1p = 0.f, c2p = 0.f;
  for (int q = 0; q < 16; ++q) {
    int l = t + (q << 8);
    int r = l >> 6, c = l & 63;
    float a = As[r * 68 + c];
    int m2 = (64 - r) & 63;
    int m3 = (64 - c) & 63;
    int m3b = (62 - c) & 63;
    c1p += a * Bs[m2 * 68 + m3];
    c2p += a * Bs[m2 * 68 + m3b];
  }
  if (paired) { c1p *= 2.f; c2p *= 2.f; }
  for (int off = 32; off; off >>= 1) {
    ssp += __shfl_down(ssp, off);
    c1p += __shfl_down(c1p, off);
    c2p += __shfl_down(c2p, off);
  }
  const int lane = t & 63, wid = t >> 6;
  if (lane == 0) { rsm[wid * 3] = ssp; rsm[wid * 3 + 1] = c1p; rsm[wid * 3 + 2] = c2p; }
  __syncthreads();   // covers PL writes + rsm
  if (t == 0) {
    red1p[((size_t)bc * 33 + j) * 3 + 0] = rsm[0] + rsm[3] + rsm[6] + rsm[9];
    red1p[((size_t)bc * 33 + j) * 3 + 1] = rsm[1] + rsm[4] + rsm[7] + rsm[10];
    red1p[((size_t)bc * 33 + j) * 3 + 2] = rsm[2] + rsm[5] + rsm[8] + rsm[11];
  }
  {  // stage 2: contract n2 for 8 k2; ds_read_b128 rows + register rotation
    const int rr = t >> 3;
    const int row = rr >> 4, f = (rr >> 3) & 1, k3 = rr & 7;
    float rc = 1.f, rs = 0.f, re = 0.f, im = 0.f;
    const float4* pr4 = (const float4*)&PL[rr * 68];
#pragma unroll 4
    for (int m = 0; m < 16; ++m) {
      float4 v = pr4[m];
      re += v.x * rc; im -= v.x * rs;
      { float nc = rc * dc2 - rs * ds2; rs = rs * dc2 + rc * ds2; rc = nc; }
      re += v.y * rc; im -= v.y * rs;
      { float nc = rc * dc2 - rs * ds2; rs = rs * dc2 + rc * ds2; rc = nc; }
      re += v.z * rc; im -= v.z * rs;
      { float nc = rc * dc2 - rs * ds2; rs = rs * dc2 + rc * ds2; rc = nc; }
      re += v.w * rc; im -= v.w * rs;
      { float nc = rc * dc2 - rs * ds2; rs = rs * dc2 + rc * ds2; rc = nc; }
    }
    const int n1row = row ? n1b : n1a;
    ((float2*)S)[(((size_t)bc * 64 + n1row) * 2 + f) * 64 + k2s * 8 + k3] =
        make_float2(re, im);
  }
}

// ---------------- K2: stage3 (n1->k1) + corner r + normalize ----------------
// grid (4,128): h splits the k2k3 range 4 ways; both f halves in-block.
__global__ __launch_bounds__(256) void k_fwd2s(const float* __restrict__ S,
                                               const float* __restrict__ red1p,
                                               float* __restrict__ xh) {
  __shared__ float2 U3L[256];     // [f][k1 8][kkl 16]
  __shared__ float2 tw[8 * 66];   // [k1][n1] pad 66 -> bank spread
  __shared__ float rbuf[99];
  const int t = threadIdx.x;
  const int h = blockIdx.x;       // 0..3
  const int bc = blockIdx.y;
  for (int u = t; u < 512; u += 256) {
    int k1 = u >> 6, n1 = u & 63;
    float ang = TWOPI_64 * (float)((k1 * n1) & 63);
    tw[k1 * 66 + n1] = make_float2(cosf(ang), sinf(ang));
  }
  if (t < 99) rbuf[t] = red1p[(size_t)bc * 99 + t];
  __syncthreads();
  {
    const int kkl = t & 15;
    const int f = (t >> 4) & 1;
    const int k1 = t >> 5;          // one k1 per thread
    const int rr2 = f * 64 + h * 16 + kkl;
    const float2* Sb = (const float2*)(S + ((size_t)bc << 14));
    const float2* tk = &tw[k1 * 66];
    float re = 0.f, im = 0.f;
#pragma unroll 4
    for (int n1 = 0; n1 < 64; ++n1) {
      float2 ab = Sb[(n1 << 7) + rr2];
      float2 cs = tk[n1];
      re += ab.x * cs.x + ab.y * cs.y;
      im += ab.y * cs.x - ab.x * cs.y;
    }
    U3L[f * 128 + k1 * 16 + kkl] = make_float2(re, im);
  }
  __syncthreads();
  float ss = 0.f, c1 = 0.f, c2 = 0.f;
  for (int jj = 0; jj < 33; ++jj) {
    ss += rbuf[jj * 3];
    c1 += rbuf[jj * 3 + 1];
    c2 += rbuf[jj * 3 + 2];
  }
  float nsq = 0.5f * (float)NT * (2.f * ss + c1 - c2);
  float inv1 = nsq > 0.f ? rsqrtf(nsq) : 0.f;
  if (t < 128) {
    const int k1 = t >> 4, kkl = t & 15;
    const int kk = h * 16 + kkl;
    const int k3 = kk & 7;
    float2 U = U3L[k1 * 16 + kkl];
    float2 V = U3L[128 + k1 * 16 + kkl];
    float2 cs = tw[k3 * 66 + 1];    // (cos(th*k3), sin(th*k3))
    float r = U.x - V.y - cs.y * (U.x + V.y) - cs.x * (U.y - V.x);
    xh[(size_t)bc * 512 + k1 * 64 + kk] = r * inv1;
  }
}

// ---------------- K3: mix + full norm + expansion A/B/C, wave-owned k1 sets ----------------
// grid (2,128): h = k1-half. Each block computes the FULL conv + norm (duplicated,
// cheap), then expansion for 32 k1: wave wid owns k1l in [wid*8, wid*8+8), with
// private A1L rows and B2 buffer -> no __syncthreads after the conv barrier.
__global__ __launch_bounds__(256) void k_mixexp(const float* __restrict__ xh,
                                                const float* __restrict__ w,
                                                float* __restrict__ out) {
  __shared__ float convL[8 * 66];    // [n1][col] pad 66
  __shared__ float A1L[32 * 132];    // [k1l][col*2] pad 132 (16B-aligned rows)
  __shared__ float B2w[4 * 64 * 20]; // per-wave [k2][f*8+n3] pad 20
  __shared__ float c64v[64], s64v[64];
  __shared__ float psum[4];
  const int t = threadIdx.x;
  const int h = blockIdx.x;          // 0..1
  const int bc2 = blockIdx.y;        // 0..127
  const int b = bc2 >> 5, o = bc2 & 31;
  if (t < 64) { float ang = TWOPI_64 * t; c64v[t] = cosf(ang); s64v[t] = sinf(ang); }
  // ---- mix: 2 k-points per thread, full 8x8x8 ----
  const float* xg = xh + ((size_t)b << 14);
  const int col = t & 63;
  const int n1m = t >> 6;            // 0..3; second point uses n1m+4
  const int n2c = col >> 3, n3c = col & 7;
  const int nkc = (((8 - n2c) & 7) << 3) + ((8 - n3c) & 7);
  const int k0 = t;
  const int nk0 = (((8 - n1m) & 7) << 6) + nkc;
  const int k1p = t + 256;
  const int nk1 = (((8 - (n1m + 4)) & 7) << 6) + nkc;
  float acc0 = 0.f, acc1 = 0.f;
  const float* wb = w + ((size_t)o << 9);
#pragma unroll 4
  for (int i = 0; i < 32; ++i) {
    const float* wr = wb + ((size_t)i << 14);
    const float* xi = xg + (i << 9);
    float xa0 = xi[k0], xn0 = xi[nk0];
    float xa1 = xi[k1p], xn1 = xi[nk1];
    acc0 += (xa0 + xn0) * wr[k0] + (xa0 - xn0) * wr[nk0];
    acc1 += (xa1 + xn1) * wr[k1p] + (xa1 - xn1) * wr[nk1];
  }
  const float c0 = 0.5f * acc0, c1v = 0.5f * acc1;
  convL[n1m * 66 + col] = c0;
  convL[(n1m + 4) * 66 + col] = c1v;
  float p = c0 * c0 + c1v * c1v;
  for (int off = 32; off; off >>= 1) p += __shfl_down(p, off);
  if ((t & 63) == 0) psum[t >> 6] = p;
  __syncthreads();   // convL + psum + c64v/s64v all visible; ONLY barrier in kernel
  const float S2 = psum[0] + psum[1] + psum[2] + psum[3];
  const float c000 = convL[0];
  const float nsq = 0.5f * (float)NT * (2.f * S2 + c000 * c000);
  const float sc = nsq > 0.f ? 1.f / (sqrtf(nsq) * (float)NT) : 0.f;
  // ---- stage A: n1 -> k1 for this wave's 8 k1; lane = col ----
  const int wid = t >> 6, l = t & 63;
  float cv[8];
#pragma unroll
  for (int n1 = 0; n1 < 8; ++n1) cv[n1] = convL[n1 * 66 + l];
#pragma unroll
  for (int it = 0; it < 8; ++it) {
    const int k1l = wid * 8 + it;
    const int k1g = (h << 5) + k1l;
    float re = 0.f, im = 0.f;
#pragma unroll
    for (int n1 = 0; n1 < 8; ++n1) {
      int a = (k1g * n1) & 63;
      re += cv[n1] * c64v[a];
      im -= cv[n1] * s64v[a];
    }
    A1L[k1l * 132 + 2 * l] = re;
    A1L[k1l * 132 + 2 * l + 1] = im;
  }
  asm volatile("s_waitcnt lgkmcnt(0)" ::: "memory");  // wave's A1L rows complete
  // ---- per-lane coefficient sets (lane doubles as k2 for B and k3 for C) ----
  float csc[8], css[8];
#pragma unroll
  for (int n2i = 0; n2i < 8; ++n2i) {
    int a = (l * n2i) & 63;
    csc[n2i] = c64v[a]; css[n2i] = s64v[a];
  }
  float C1r[8], C2r[8];
#pragma unroll
  for (int n3 = 0; n3 < 8; ++n3) {
    int a0 = (l * n3) & 63;
    int a1 = (l * (n3 + 1)) & 63;
    C1r[n3] = c64v[a0] - s64v[a1];
    C2r[n3] = s64v[a0] - c64v[a1];
  }
  // ---- expansion loop: 8 k1 per wave, stage B then C, wave-private B2 buffer ----
  float* B2r = &B2w[wid * 1280];
  float* outb = out + ((size_t)bc2 << 18);
  for (int it = 0; it < 8; ++it) {
    const int k1l = wid * 8 + it;
    const int k1g = (h << 5) + k1l;
    const float* Arow = &A1L[k1l * 132];
    // stage B: lane = k2; all 16 (f,n3) accs; Arow reads are wave-uniform broadcasts
    float f0[8] = {0, 0, 0, 0, 0, 0, 0, 0};
    float f1[8] = {0, 0, 0, 0, 0, 0, 0, 0};
#pragma unroll
    for (int n2i = 0; n2i < 8; ++n2i) {
      const float4* a4 = (const float4*)&Arow[n2i << 4];
      float4 q0 = a4[0], q1 = a4[1], q2 = a4[2], q3 = a4[3];
      float tc = csc[n2i], ts = css[n2i];
      f0[0] += q0.x * tc + q0.y * ts;  f1[0] += q0.y * tc - q0.x * ts;
      f0[1] += q0.z * tc + q0.w * ts;  f1[1] += q0.w * tc - q0.z * ts;
      f0[2] += q1.x * tc + q1.y * ts;  f1[2] += q1.y * tc - q1.x * ts;
      f0[3] += q1.z * tc + q1.w * ts;  f1[3] += q1.w * tc - q1.z * ts;
      f0[4] += q2.x * tc + q2.y * ts;  f1[4] += q2.y * tc - q2.x * ts;
      f0[5] += q2.z * tc + q2.w * ts;  f1[5] += q2.w * tc - q2.z * ts;
      f0[6] += q3.x * tc + q3.y * ts;  f1[6] += q3.y * tc - q3.x * ts;
      f0[7] += q3.z * tc + q3.w * ts;  f1[7] += q3.w * tc - q3.z * ts;
    }
    float* br = &B2r[l * 20];
    *(float4*)&br[0]  = make_float4(f0[0], f0[1], f0[2], f0[3]);
    *(float4*)&br[4]  = make_float4(f0[4], f0[5], f0[6], f0[7]);
    *(float4*)&br[8]  = make_float4(f1[0], f1[1], f1[2], f1[3]);
    *(float4*)&br[12] = make_float4(f1[4], f1[5], f1[6], f1[7]);
    asm volatile("s_waitcnt lgkmcnt(0)" ::: "memory");  // B2 row writes complete (same wave)
    // stage C: lane = k3; B2 reads wave-uniform broadcasts; coalesced stores
    float* dst = outb + ((size_t)k1g << 12);
#pragma unroll 4
    for (int k2 = 0; k2 < 64; ++k2) {
      const float4* b4 = (const float4*)&B2r[k2 * 20];
      float4 r0 = b4[0], r1 = b4[1], r2 = b4[2], r3 = b4[3];
      float acc = r0.x * C1r[0] + r0.y * C1r[1] + r0.z * C1r[2] + r0.w * C1r[3]
                + r1.x * C1r[4] + r1.y * C1r[5] + r1.z * C1r[6] + r1.w * C1r[7]
                + r2.x * C2r[0] + r2.y * C2r[1] + r2.z * C2r[2] + r2.w * C2r[3]
                + r3.x * C2r[4] + r3.y * C2r[5] + r3.z * C2r[6] + r3.w * C2r[7];
      dst[(k2 << 6) + l] = acc * sc;
    }
    // next iteration's B-writes are same-wave DS ops issued after C's reads: in-order DS
    // pipeline makes the WAR safe without an extra wait.
  }
}

extern "C" void kernel_launch(void* const* d_in, const int* in_sizes, int n_in,
                              void* d_out, int out_size, void* d_ws, size_t ws_size,
                              hipStream_t stream) {
  const float* x = (const float*)d_in[0];
  const float* w = (const float*)d_in[1];
  float* out = (float*)d_out;
  float* ws = (float*)d_ws;
  float* S     = ws;
  float* red1p = ws + 2097152;
  float* xh    = ws + 2109824;

  k_fwd1  <<<dim3(33, 128), 256, 0, stream>>>(x, S, red1p);
  k_fwd2s <<<dim3(4, 128),  256, 0, stream>>>(S, red1p, xh);
  k_mixexp<<<dim3(2, 128),  256, 0, stream>>>(xh, w, out);
}

// Round 6
// 285.274 us; speedup vs baseline: 1.0469x; 1.0469x over previous
//
#include <hip/hip_runtime.h>
#include <math.h>

// SpectralConv3d via DHT identities — R6: expBC de-transposed (LDS-pipe theory).
//   r = Re(F) - Im(G);  ||r||^2 = (N^3/2)(2*sum x^2 + c1 - c2)
//   corner: n3->k3 + n2->k2 fused (k_fwd1), n1->k1 (k_fwd2s)
//   mix: conv = 0.5*sum_i[(x+xn)w + (x-xn)wn]; ||Y||^2 = (N^3/2)(2*sum conv^2 + conv000^2)
//   expand: n1->k1 (A1), then per-wave: P/Q = n3-contraction (regs), k2-loop with
//   wave-uniform coef loads — NO B2 buffer, no LDS transpose.
//
// R6 vs R1 (271.3us): k_expBC rewritten. R5 probe measured T1+T4 ~ 60us/iter and
// cycle model attributes ~40us of that to expBC's 320 ds_read_b128 broadcasts per
// block (single LDS pipe, 32 blocks/CU). New form: 34 LDS ops per k1-tile; k2-loop
// coefs from a 4KB global table (scalar/K$ path), built by fwd1 block(0,0).
// fwd1/fwd2s/mixA are byte-identical to R1.

constexpr int NT = 262144;  // 64^3
constexpr float TWOPI_64 = 0.09817477042468103f;  // 2*pi/64

// ws float offsets:
//   S     [128][64][2][64][2] : 2097152 at 0
//   red1p [128][33][3]        : 12672   at 2097152
//   xh    [128][512]          : 65536   at 2109824
//   inv2q [128][2]            : 256     at 2175360
//   A1    [128][8192]         : 1048576 at 2175616
//   TB2g  [64][16]            : 1024    at 3224192   (c,s)(T*k2*n2) k2-major

// ---------------- K1: stage1 (n3->k3) + stage2 (n2->k2) + norm partials ----------------
__global__ __launch_bounds__(256) void k_fwd1(const float* __restrict__ x,
                                              float* __restrict__ S,
                                              float* __restrict__ red1p,
                                              float* __restrict__ TB2g) {
  __shared__ float As[64 * 68];   // pad 68: 16B-aligned rows for ds_read_b128
  __shared__ float Bs[64 * 68];
  __shared__ float PL[32 * 65];   // stage1 output: rr = row*16 + f*8 + k3
  __shared__ float tw1[1024];     // [n3 64][k3q 4][c(k3q),s(k3q),c(k3q+4),s(k3q+4)]
  __shared__ float rsm[12];
  const int t = threadIdx.x;
  const int j = blockIdx.x;       // 0..32
  const int bc = blockIdx.y;      // 0..127
  const int n1a = j, n1b = (64 - j) & 63;
  const bool paired = (n1a != n1b);
  // piggyback: block (0,0) builds the expBC coefficient table (global, K$-served)
  if (j == 0 && bc == 0) {
    for (int u = t; u < 1024; u += 256) {
      int k2 = u >> 4, i = u & 15, n2 = i >> 1;
      float ang = TWOPI_64 * (float)((k2 * n2) & 63);
      TB2g[u] = (i & 1) ? sinf(ang) : cosf(ang);
    }
  }
  for (int u = t; u < 1024; u += 256) {
    int n3 = u >> 4, k3q_ = (u >> 2) & 3, jj = u & 3;
    int k3 = k3q_ + ((jj >> 1) << 2);
    float ang = TWOPI_64 * (float)((k3 * n3) & 63);
    tw1[u] = (jj & 1) ? sinf(ang) : cosf(ang);
  }
  const float4* xa4 = (const float4*)(x + ((size_t)bc << 18) + (n1a << 12));
  const float4* xb4 = (const float4*)(x + ((size_t)bc << 18) + (n1b << 12));
  float ssp = 0.f;
  for (int q = 0; q < 4; ++q) {
    int l4 = t + (q << 8);
    int fl = l4 << 2;
    int r = fl >> 6, c = fl & 63;
    float4 va = xa4[l4], vb = xb4[l4];
    *(float4*)&As[r * 68 + c] = va;
    *(float4*)&Bs[r * 68 + c] = vb;
    ssp += va.x * va.x + va.y * va.y + va.z * va.z + va.w * va.w;
    if (paired) ssp += vb.x * vb.x + vb.y * vb.y + vb.z * vb.z + vb.w * vb.w;
  }
  __syncthreads();
  const int n2 = t & 63;
  const int k3q = t >> 6;
  {  // stage 1: contract n3 for k3q,k3q+4 over rows A,B; tw1 b128 wave-uniform broadcast
    float reA0 = 0, imA0 = 0, reA1 = 0, imA1 = 0;
    float reB0 = 0, imB0 = 0, reB1 = 0, imB1 = 0;
    const float4* Ar = (const float4*)&As[n2 * 68];
    const float4* Br = (const float4*)&Bs[n2 * 68];
    const float4* T4 = (const float4*)tw1;
    for (int m = 0; m < 16; ++m) {
      float4 va = Ar[m], vb = Br[m];
      float av[4] = {va.x, va.y, va.z, va.w};
      float bv[4] = {vb.x, vb.y, vb.z, vb.w};
#pragma unroll
      for (int e = 0; e < 4; ++e) {
        float4 tw = T4[(m << 4) + (e << 2) + k3q];
        float a = av[e], b = bv[e];
        reA0 += a * tw.x; imA0 -= a * tw.y;
        reB0 += b * tw.x; imB0 -= b * tw.y;
        reA1 += a * tw.z; imA1 -= a * tw.w;
        reB1 += b * tw.z; imB1 -= b * tw.w;
      }
    }
    PL[(k3q) * 65 + n2] = reA0;       PL[(8 + k3q) * 65 + n2] = imA0;
    PL[(16 + k3q) * 65 + n2] = reB0;  PL[(24 + k3q) * 65 + n2] = imB0;
    PL[(4 + k3q) * 65 + n2] = reA1;   PL[(12 + k3q) * 65 + n2] = imA1;
    PL[(20 + k3q) * 65 + n2] = reB1;  PL[(28 + k3q) * 65 + n2] = imB1;
  }
  // norm partials c1,c2 (ss done at load)
  float c1p = 0.f, c2p = 0.f;
  for (int q = 0; q < 16; ++q) {
    int l = t + (q << 8);
    int r = l >> 6, c = l & 63;
    float a = As[r * 68 + c];
    int m2 = (64 - r) & 63;
    int m3 = (64 - c) & 63;
    int m3b = (62 - c) & 63;
    c1p += a * Bs[m2 * 68 + m3];
    c2p += a * Bs[m2 * 68 + m3b];
  }
  if (paired) { c1p *= 2.f; c2p *= 2.f; }
  for (int off = 32; off; off >>= 1) {
    ssp += __shfl_down(ssp, off);
    c1p += __shfl_down(c1p, off);
    c2p += __shfl_down(c2p, off);
  }
  const int lane = t & 63, wid = t >> 6;
  if (lane == 0) { rsm[wid * 3] = ssp; rsm[wid * 3 + 1] = c1p; rsm[wid * 3 + 2] = c2p; }
  __syncthreads();   // covers PL writes + rsm
  if (t == 0) {
    red1p[((size_t)bc * 33 + j) * 3 + 0] = rsm[0] + rsm[3] + rsm[6] + rsm[9];
    red1p[((size_t)bc * 33 + j) * 3 + 1] = rsm[1] + rsm[4] + rsm[7] + rsm[10];
    red1p[((size_t)bc * 33 + j) * 3 + 2] = rsm[2] + rsm[5] + rsm[8] + rsm[11];
  }
  {  // stage 2: contract n2 for 8 k2; twiddles from tw1 (8 distinct banks, conflict-free)
    const int k2 = t & 7;
    const int rr = t >> 3;
    const int row = rr >> 4, f = (rr >> 3) & 1, k3 = rr & 7;
    float re = 0.f, im = 0.f;
    const float* pr = &PL[rr * 65];
    const int tb = ((k2 & 3) << 2) + ((k2 >> 2) << 1);
#pragma unroll 4
    for (int n2i = 0; n2i < 64; ++n2i) {
      float v = pr[n2i];
      const float2 cs = *(const float2*)&tw1[(n2i << 4) + tb];
      re += v * cs.x; im -= v * cs.y;
    }
    const int n1row = row ? n1b : n1a;
    ((float2*)S)[(((size_t)bc * 64 + n1row) * 2 + f) * 64 + k2 * 8 + k3] =
        make_float2(re, im);
  }
}

// ---------------- K2: stage3 (n1->k1) + corner r + normalize ----------------
__global__ __launch_bounds__(256) void k_fwd2s(const float* __restrict__ S,
                                               const float* __restrict__ red1p,
                                               float* __restrict__ xh) {
  __shared__ float2 U3L[256];     // [f][k1 8][kkl 16]
  __shared__ float2 tw[8 * 66];   // [k1][n1] pad 66 -> bank spread
  __shared__ float rbuf[99];
  const int t = threadIdx.x;
  const int h = blockIdx.x;       // 0..3
  const int bc = blockIdx.y;
  for (int u = t; u < 512; u += 256) {
    int k1 = u >> 6, n1 = u & 63;
    float ang = TWOPI_64 * (float)((k1 * n1) & 63);
    tw[k1 * 66 + n1] = make_float2(cosf(ang), sinf(ang));
  }
  if (t < 99) rbuf[t] = red1p[(size_t)bc * 99 + t];
  __syncthreads();
  {
    const int kkl = t & 15;
    const int f = (t >> 4) & 1;
    const int k1 = t >> 5;          // one k1 per thread
    const int rr2 = f * 64 + h * 16 + kkl;
    const float2* Sb = (const float2*)(S + ((size_t)bc << 14));
    const float2* tk = &tw[k1 * 66];
    float re = 0.f, im = 0.f;
#pragma unroll 4
    for (int n1 = 0; n1 < 64; ++n1) {
      float2 ab = Sb[(n1 << 7) + rr2];
      float2 cs = tk[n1];
      re += ab.x * cs.x + ab.y * cs.y;
      im += ab.y * cs.x - ab.x * cs.y;
    }
    U3L[f * 128 + k1 * 16 + kkl] = make_float2(re, im);
  }
  __syncthreads();
  float ss = 0.f, c1 = 0.f, c2 = 0.f;
  for (int jj = 0; jj < 33; ++jj) {
    ss += rbuf[jj * 3];
    c1 += rbuf[jj * 3 + 1];
    c2 += rbuf[jj * 3 + 2];
  }
  float nsq = 0.5f * (float)NT * (2.f * ss + c1 - c2);
  float inv1 = nsq > 0.f ? rsqrtf(nsq) : 0.f;
  if (t < 128) {
    const int k1 = t >> 4, kkl = t & 15;
    const int kk = h * 16 + kkl;
    const int k3 = kk & 7;
    float2 U = U3L[k1 * 16 + kkl];
    float2 V = U3L[128 + k1 * 16 + kkl];
    float2 cs = tw[k3 * 66 + 1];    // (cos(th*k3), sin(th*k3))
    float r = U.x - V.y - cs.y * (U.x + V.y) - cs.x * (U.y - V.x);
    xh[(size_t)bc * 512 + k1 * 64 + kk] = r * inv1;
  }
}

// ---------------- K3: channel mixing + expansion stage A + norm partials ----------------
__global__ __launch_bounds__(256) void k_mixA(const float* __restrict__ xh,
                                              const float* __restrict__ w,
                                              float* __restrict__ A1,
                                              float* __restrict__ inv2q) {
  __shared__ float xsh[16384];    // 64 KB: full xh slice for this b
  __shared__ float convL[8 * 33]; // [n1][col32] pad 33
  __shared__ float c64v[64], s64v[64];
  __shared__ float psum[4];
  const int t = threadIdx.x;
  const int bh = blockIdx.x;
  const int h = bh & 1;
  const int bc2 = bh >> 1;
  const int b = bc2 >> 5, o = bc2 & 31;
  if (t < 64) { float ang = TWOPI_64 * t; c64v[t] = cosf(ang); s64v[t] = sinf(ang); }
  const float4* xb4 = (const float4*)(xh + ((size_t)b << 14));
  float4* xs4 = (float4*)xsh;
  for (int q = 0; q < 16; ++q) xs4[t + (q << 8)] = xb4[t + (q << 8)];
  __syncthreads();
  const int n1m = t >> 5;
  const int col32 = t & 31;
  const int col = (h << 5) + col32;
  const int n2 = col >> 3, n3 = col & 7;
  const int k = (n1m << 6) + col;
  const int nk = (((8 - n1m) & 7) << 6) + (((8 - n2) & 7) << 3) + ((8 - n3) & 7);
  float acc = 0.f;
  const float* wb = w + ((size_t)o << 9);
#pragma unroll 4
  for (int i = 0; i < 32; ++i) {
    const float* wr = wb + ((size_t)i << 14);
    float xa = xsh[(i << 9) + k], xn = xsh[(i << 9) + nk];
    acc += (xa + xn) * wr[k] + (xa - xn) * wr[nk];
  }
  const float cval = 0.5f * acc;
  convL[n1m * 33 + col32] = cval;
  float p = cval * cval;
  for (int off = 32; off; off >>= 1) p += __shfl_down(p, off);
  if ((t & 63) == 0) psum[t >> 6] = p;
  __syncthreads();   // covers convL + psum
  if (t == 0) {
    float Q = 2.f * (psum[0] + psum[1] + psum[2] + psum[3]);
    if (h == 0) { float c000 = convL[0]; Q += c000 * c000; }
    inv2q[bc2 * 2 + h] = Q;
  }
  const int q8 = t >> 5;
  float cv[8];
#pragma unroll
  for (int n1i = 0; n1i < 8; ++n1i) cv[n1i] = convL[n1i * 33 + col32];
  float2* A1p = (float2*)(A1 + ((size_t)bc2 << 13));
  for (int it = 0; it < 8; ++it) {
    const int k1 = q8 + (it << 3);
    float re = 0.f, im = 0.f;
#pragma unroll
    for (int n1i = 0; n1i < 8; ++n1i) {
      int a = (k1 * n1i) & 63;
      re += cv[n1i] * c64v[a];
      im -= cv[n1i] * s64v[a];
    }
    A1p[(k1 << 6) + col] = make_float2(re, im);
  }
}

// ---------------- K4: expansion B+C de-transposed: P/Q in regs, uniform coef loads ----------------
// grid (16,128): 4 waves/block, each wave owns one k1 = blockIdx.x*4 + wid; lane = k3.
//   P[n2] = sum_n3 a[n2][n3]*C1[k3][n3] + b[n2][n3]*C2[k3][n3]
//   Q[n2] = sum_n3 b[n2][n3]*C1[k3][n3] - a[n2][n3]*C2[k3][n3]
//   out[k2][k3] = sc * sum_n2 c2[k2][n2]*P[n2] + s2[k2][n2]*Q[n2]
// LDS per k1: 32 b128 broadcast reads (A row) + staging — vs 330 in the old B2 form.
__global__ __launch_bounds__(256) void k_expBC(const float* __restrict__ A1,
                                               const float* __restrict__ inv2q,
                                               const float* __restrict__ TB2g,
                                               float* __restrict__ out) {
  __shared__ float arows[512];    // 4 k1 rows x 128 floats
  __shared__ float c64v[64], s64v[64];
  const int t = threadIdx.x;
  const int k1g = blockIdx.x;     // 0..15
  const int bc2 = blockIdx.y;     // 0..127
  const int wid = t >> 6, lane = t & 63;
  if (t < 64) { float ang = TWOPI_64 * t; c64v[t] = cosf(ang); s64v[t] = sinf(ang); }
  if (t < 128) {                  // stage 4 A1 rows (coalesced float4)
    const float4* src = (const float4*)(A1 + ((size_t)bc2 << 13) + (k1g << 9));
    ((float4*)arows)[t] = src[t];
  }
  __syncthreads();
  // per-lane flip coefficients (k3 = lane)
  float C1r[8], C2r[8];
#pragma unroll
  for (int n3 = 0; n3 < 8; ++n3) {
    int a0 = (lane * n3) & 63;
    int a1 = (lane * (n3 + 1)) & 63;
    C1r[n3] = c64v[a0] - s64v[a1];
    C2r[n3] = s64v[a0] - c64v[a1];
  }
  // P/Q: contract n3 over this wave's A row (b128 wave-uniform broadcasts)
  float P[8], Q[8];
  const float4* Ar = (const float4*)&arows[wid << 7];
#pragma unroll
  for (int n2 = 0; n2 < 8; ++n2) {
    float4 q0 = Ar[n2 * 4 + 0];   // a0,b0,a1,b1
    float4 q1 = Ar[n2 * 4 + 1];   // a2,b2,a3,b3
    float4 q2 = Ar[n2 * 4 + 2];   // a4,b4,a5,b5
    float4 q3 = Ar[n2 * 4 + 3];   // a6,b6,a7,b7
    float p = 0.f, qq = 0.f;
    p  += q0.x * C1r[0] + q0.y * C2r[0] + q0.z * C1r[1] + q0.w * C2r[1];
    qq += q0.y * C1r[0] - q0.x * C2r[0] + q0.w * C1r[1] - q0.z * C2r[1];
    p  += q1.x * C1r[2] + q1.y * C2r[2] + q1.z * C1r[3] + q1.w * C2r[3];
    qq += q1.y * C1r[2] - q1.x * C2r[2] + q1.w * C1r[3] - q1.z * C2r[3];
    p  += q2.x * C1r[4] + q2.y * C2r[4] + q2.z * C1r[5] + q2.w * C2r[5];
    qq += q2.y * C1r[4] - q2.x * C2r[4] + q2.w * C1r[5] - q2.z * C2r[5];
    p  += q3.x * C1r[6] + q3.y * C2r[6] + q3.z * C1r[7] + q3.w * C2r[7];
    qq += q3.y * C1r[6] - q3.x * C2r[6] + q3.w * C1r[7] - q3.z * C2r[7];
    P[n2] = p; Q[n2] = qq;
  }
  // normalization
  const float q0v = inv2q[bc2 * 2], q1v = inv2q[bc2 * 2 + 1];
  const float nsq = 0.5f * (float)NT * (q0v + q1v);
  const float sc = nsq > 0.f ? 1.f / (sqrtf(nsq) * (float)NT) : 0.f;
  // k2 loop: wave-uniform coef loads (scalar/K$ path) + 16 FMA + coalesced store
  const int k1 = (k1g << 2) + wid;
  float* dst = out + ((size_t)bc2 << 18) + (k1 << 12);
#pragma unroll 4
  for (int k2 = 0; k2 < 64; ++k2) {
    const int k2u = __builtin_amdgcn_readfirstlane(k2);
    const float4* TBk = (const float4*)(TB2g + (k2u << 4));
    float4 t0 = TBk[0], t1 = TBk[1], t2 = TBk[2], t3 = TBk[3];
    float acc = t0.x * P[0] + t0.y * Q[0] + t0.z * P[1] + t0.w * Q[1]
              + t1.x * P[2] + t1.y * Q[2] + t1.z * P[3] + t1.w * Q[3]
              + t2.x * P[4] + t2.y * Q[4] + t2.z * P[5] + t2.w * Q[5]
              + t3.x * P[6] + t3.y * Q[6] + t3.z * P[7] + t3.w * Q[7];
    dst[(k2 << 6) + lane] = acc * sc;
  }
}

extern "C" void kernel_launch(void* const* d_in, const int* in_sizes, int n_in,
                              void* d_out, int out_size, void* d_ws, size_t ws_size,
                              hipStream_t stream) {
  const float* x = (const float*)d_in[0];
  const float* w = (const float*)d_in[1];
  float* out = (float*)d_out;
  float* ws = (float*)d_ws;
  float* S     = ws;
  float* red1p = ws + 2097152;
  float* xh    = ws + 2109824;
  float* inv2q = ws + 2175360;
  float* A1    = ws + 2175616;
  float* TB2g  = ws + 3224192;

  k_fwd1 <<<dim3(33, 128), 256, 0, stream>>>(x, S, red1p, TB2g);
  k_fwd2s<<<dim3(4, 128),  256, 0, stream>>>(S, red1p, xh);
  k_mixA <<<dim3(256),     256, 0, stream>>>(xh, w, A1, inv2q);
  k_expBC<<<dim3(16, 128), 256, 0, stream>>>(A1, inv2q, TB2g, out);
}